// Round 4
// baseline (2106.143 us; speedup 1.0000x reference)
//
#include <hip/hip_runtime.h>
#include <stdint.h>

#define TT 8192
#define DD 5120
#define HH 13824

typedef int v4i __attribute__((ext_vector_type(4)));

#define AS1(p) ((const __attribute__((address_space(1))) void*)(p))
#define AS3(p) ((__attribute__((address_space(3))) void*)(p))

__device__ __forceinline__ float wave_max64(float v) {
#pragma unroll
  for (int off = 32; off > 0; off >>= 1)
    v = fmaxf(v, __shfl_xor(v, off, 64));
  return v;
}
__device__ __forceinline__ int wave_sum64(int v) {
#pragma unroll
  for (int off = 32; off > 0; off >>= 1)
    v += __shfl_xor(v, off, 64);
  return v;
}

// ---------------- weight convert: int32 codes (0..255) -> int8 (code-128) ----------------
__global__ __launch_bounds__(256) void cvt_w(const int* __restrict__ w,
                                             int8_t* __restrict__ o, int n16) {
  const int4* w4 = (const int4*)w;
  int4* o4 = (int4*)o;
  int i = blockIdx.x * blockDim.x + threadIdx.x;
  int stride = gridDim.x * blockDim.x;
  for (; i < n16; i += stride) {
    int4 a = w4[(size_t)i * 4 + 0];
    int4 b = w4[(size_t)i * 4 + 1];
    int4 c = w4[(size_t)i * 4 + 2];
    int4 d = w4[(size_t)i * 4 + 3];
    int4 r;
    r.x = ((a.x - 128) & 0xff) | (((a.y - 128) & 0xff) << 8) |
          (((a.z - 128) & 0xff) << 16) | (((a.w - 128) & 0xff) << 24);
    r.y = ((b.x - 128) & 0xff) | (((b.y - 128) & 0xff) << 8) |
          (((b.z - 128) & 0xff) << 16) | (((b.w - 128) & 0xff) << 24);
    r.z = ((c.x - 128) & 0xff) | (((c.y - 128) & 0xff) << 8) |
          (((c.z - 128) & 0xff) << 16) | (((c.w - 128) & 0xff) << 24);
    r.w = ((d.x - 128) & 0xff) | (((d.y - 128) & 0xff) << 8) |
          (((d.z - 128) & 0xff) << 16) | (((d.w - 128) & 0xff) << 24);
    o4[i] = r;
  }
}

// ---------------- per-token dynamic quant of x [TT, DD] ----------------
__global__ __launch_bounds__(256) void quant_x(const float* __restrict__ x,
                                               int8_t* __restrict__ q,
                                               float* __restrict__ s_out,
                                               float* __restrict__ sum_out) {
  const int row = blockIdx.x;
  const int tid = threadIdx.x;
  const float4* xr = (const float4*)(x + (size_t)row * DD);
  float4 v[5];
  float m = 0.f;
#pragma unroll
  for (int r = 0; r < 5; ++r) {
    v[r] = xr[tid + r * 256];
    m = fmaxf(m, fmaxf(fmaxf(fabsf(v[r].x), fabsf(v[r].y)),
                       fmaxf(fabsf(v[r].z), fabsf(v[r].w))));
  }
  __shared__ float redf[4];
  __shared__ int redi[4];
  float wm = wave_max64(m);
  int wid = tid >> 6, lane = tid & 63;
  if (lane == 0) redf[wid] = wm;
  __syncthreads();
  float mm = fmaxf(fmaxf(redf[0], redf[1]), fmaxf(redf[2], redf[3]));
  float s = fmaxf(mm / 127.0f, 1e-8f);

  int lsum = 0;
  int* qr = (int*)(q + (size_t)row * DD);
#pragma unroll
  for (int r = 0; r < 5; ++r) {
    float a = fminf(127.f, fmaxf(-127.f, rintf(v[r].x / s)));
    float b = fminf(127.f, fmaxf(-127.f, rintf(v[r].y / s)));
    float c = fminf(127.f, fmaxf(-127.f, rintf(v[r].z / s)));
    float d = fminf(127.f, fmaxf(-127.f, rintf(v[r].w / s)));
    int ia = (int)a, ib = (int)b, ic = (int)c, id = (int)d;
    lsum += ia + ib + ic + id;
    qr[tid + r * 256] = (ia & 0xff) | ((ib & 0xff) << 8) | ((ic & 0xff) << 16) |
                        ((id & 0xff) << 24);
  }
  int wsum = wave_sum64(lsum);
  if (lane == 0) redi[wid] = wsum;
  __syncthreads();
  if (tid == 0) {
    s_out[row] = s;
    sum_out[row] = (float)(redi[0] + redi[1] + redi[2] + redi[3]);
  }
}

// ---------------- per-token dynamic quant of g [TT, HH] ----------------
__global__ __launch_bounds__(256) void quant_g(const float* __restrict__ g,
                                               int8_t* __restrict__ q,
                                               float* __restrict__ s_out,
                                               float* __restrict__ sum_out) {
  const int row = blockIdx.x;
  const int tid = threadIdx.x;
  const float4* gr = (const float4*)(g + (size_t)row * HH);
  float4 v[14];
  float m = 0.f;
#pragma unroll
  for (int r = 0; r < 14; ++r) {
    int idx = r * 256 + tid;
    if (idx < HH / 4) {
      v[r] = gr[idx];
      m = fmaxf(m, fmaxf(fmaxf(fabsf(v[r].x), fabsf(v[r].y)),
                         fmaxf(fabsf(v[r].z), fabsf(v[r].w))));
    }
  }
  __shared__ float redf[4];
  __shared__ int redi[4];
  float wm = wave_max64(m);
  int wid = tid >> 6, lane = tid & 63;
  if (lane == 0) redf[wid] = wm;
  __syncthreads();
  float mm = fmaxf(fmaxf(redf[0], redf[1]), fmaxf(redf[2], redf[3]));
  float s = fmaxf(mm / 127.0f, 1e-8f);

  int lsum = 0;
  int* qr = (int*)(q + (size_t)row * HH);
#pragma unroll
  for (int r = 0; r < 14; ++r) {
    int idx = r * 256 + tid;
    if (idx < HH / 4) {
      float a = fminf(127.f, fmaxf(-127.f, rintf(v[r].x / s)));
      float b = fminf(127.f, fmaxf(-127.f, rintf(v[r].y / s)));
      float c = fminf(127.f, fmaxf(-127.f, rintf(v[r].z / s)));
      float d = fminf(127.f, fmaxf(-127.f, rintf(v[r].w / s)));
      int ia = (int)a, ib = (int)b, ic = (int)c, id = (int)d;
      lsum += ia + ib + ic + id;
      qr[idx] = (ia & 0xff) | ((ib & 0xff) << 8) | ((ic & 0xff) << 16) |
                ((id & 0xff) << 24);
    }
  }
  int wsum = wave_sum64(lsum);
  if (lane == 0) redi[wid] = wsum;
  __syncthreads();
  if (tid == 0) {
    s_out[row] = s;
    sum_out[row] = (float)(redi[0] + redi[1] + redi[2] + redi[3]);
  }
}

// ================= 256x256 8-phase i8 GEMM (T2+T3+T4+T5 port, r4) =================
// Same structure/addressing as r3 (refcheck'd). r4 deltas:
//  (a) MFMA16 reordered: 8 independent k-slice-0 MFMAs, then 8 k-slice-1
//      (dep distance 8 instead of 1).
//  (b) no asm lgkmcnt(0): C++ ds_reads -> compiler emits counted per-use
//      lgkmcnt; slice-0 fragments issued first so slice-1 completes under
//      slice-0 MFMAs. Buffer validity still guarded by asm vmcnt(7)+barrier.
#define BAR_() __builtin_amdgcn_s_barrier()
#define WAITV7_() asm volatile("s_waitcnt vmcnt(7)" ::: "memory")

#define STAGE_AQ(B_, KT_, Q_)                                                  \
  __builtin_amdgcn_global_load_lds(                                            \
      AS1(Aptr + (size_t)(tm0 + aq_row0 + (Q_)*32) * Ks + (size_t)(KT_)*128 +  \
          st_c),                                                               \
      AS3(lds + (B_)*65536 + a_dst_w + (Q_)*4096), 16, 0, 0)

#define STAGE_BH(B_, KT_, H_, R_)                                              \
  __builtin_amdgcn_global_load_lds(                                            \
      AS1(Bptr + (size_t)(tn0 + (H_)*128 + (R_)*64 + b_row0) * Ks +            \
          (size_t)(KT_)*128 + st_c),                                           \
      AS3(lds + (B_)*65536 + 32768 + (H_)*16384 + (R_)*8192 + wid * 1024), 16, \
      0, 0)

#define DS_B0(B_)                                                              \
  {                                                                            \
    const int8_t* _pb = &lds[(B_)*65536 + 32768 + bRowOff];                    \
    bf0 = *(const v4i*)(_pb + col0);                                           \
    bf2 = *(const v4i*)(_pb + 2048 + col0);                                    \
    bf4 = *(const v4i*)(_pb + 4096 + col0);                                    \
    bf6 = *(const v4i*)(_pb + 6144 + col0);                                    \
  }
#define DS_B1(B_)                                                              \
  {                                                                            \
    const int8_t* _pb = &lds[(B_)*65536 + 32768 + bRowOff];                    \
    bf1 = *(const v4i*)(_pb + col1);                                           \
    bf3 = *(const v4i*)(_pb + 2048 + col1);                                    \
    bf5 = *(const v4i*)(_pb + 4096 + col1);                                    \
    bf7 = *(const v4i*)(_pb + 6144 + col1);                                    \
  }
#define DS_A0(B_, Q_)                                                          \
  {                                                                            \
    const int8_t* _pa = &lds[(B_)*65536 + aRowOff + (Q_)*4096];                \
    af0 = *(const v4i*)(_pa + col0);                                           \
    af2 = *(const v4i*)(_pa + 2048 + col0);                                    \
  }
#define DS_A1(B_, Q_)                                                          \
  {                                                                            \
    const int8_t* _pa = &lds[(B_)*65536 + aRowOff + (Q_)*4096];                \
    af1 = *(const v4i*)(_pa + col1);                                           \
    af3 = *(const v4i*)(_pa + 2048 + col1);                                    \
  }

#define MM(A_, B_, C_) C_ = __builtin_amdgcn_mfma_i32_16x16x64_i8(A_, B_, C_, 0, 0, 0)
// k-slice 0: 8 independent MFMAs; k-slice 1: deps at distance 8
#define MFMA16(Q_)                                                             \
  MM(af0, bf0, acc[(Q_)*2][0]);                                                \
  MM(af0, bf2, acc[(Q_)*2][1]);                                                \
  MM(af0, bf4, acc[(Q_)*2][2]);                                                \
  MM(af0, bf6, acc[(Q_)*2][3]);                                                \
  MM(af2, bf0, acc[(Q_)*2 + 1][0]);                                            \
  MM(af2, bf2, acc[(Q_)*2 + 1][1]);                                            \
  MM(af2, bf4, acc[(Q_)*2 + 1][2]);                                            \
  MM(af2, bf6, acc[(Q_)*2 + 1][3]);                                            \
  MM(af1, bf1, acc[(Q_)*2][0]);                                                \
  MM(af1, bf3, acc[(Q_)*2][1]);                                                \
  MM(af1, bf5, acc[(Q_)*2][2]);                                                \
  MM(af1, bf7, acc[(Q_)*2][3]);                                                \
  MM(af3, bf1, acc[(Q_)*2 + 1][0]);                                            \
  MM(af3, bf3, acc[(Q_)*2 + 1][1]);                                            \
  MM(af3, bf5, acc[(Q_)*2 + 1][2]);                                            \
  MM(af3, bf7, acc[(Q_)*2 + 1][3]);

#define PH(B_, Q_)                                                             \
  BAR_();                                                                      \
  __builtin_amdgcn_s_setprio(1);                                               \
  MFMA16(Q_);                                                                  \
  __builtin_amdgcn_s_setprio(0)

template <bool GELU>
__global__ __launch_bounds__(512, 2) void gemm8p(
    const int8_t* __restrict__ Aptr, const int8_t* __restrict__ Bptr,
    float* __restrict__ OUT, const float* __restrict__ sx,
    const float* __restrict__ sumx, const float* __restrict__ wsc,
    const float* __restrict__ wzp, const float* __restrict__ bias, int M,
    int N, int K) {
  extern __shared__ int8_t lds[];
  const int tid = threadIdx.x;
  const int lane = tid & 63;
  const int wid = tid >> 6;

  // XCD swizzle (requires gridDim.y==32, total%8==0)
  const int bid = blockIdx.y * gridDim.x + blockIdx.x;
  const int t = bid >> 3;
  const int ty = (bid & 7) * 4 + (t & 3);
  const int tx = t >> 2;
  const int tm0 = ty * 256;
  const int tn0 = tx * 256;

  const int wm = wid >> 2;  // 0..1
  const int wn = wid & 3;   // 0..3

  // read-side addresses
  const int col0 = (((lane >> 4) ^ (lane & 7)) << 4);
  const int col1 = col0 ^ 64;
  const int aRowOff = (wm * 128 + (lane & 15)) * 128;
  const int bRowOff = (wn * 64 + (lane & 15)) * 128;

  // stage-side addresses
  const int st_c = (((tid & 7) ^ ((tid >> 3) & 7)) << 4);  // inverse swizzle
  const int aq_row0 = ((tid & 255) >> 3) + (tid >> 8) * 128;
  const int b_row0 = tid >> 3;
  const int a_dst_w = (wid >> 2) * 16384 + (wid & 3) * 1024;  // wave-uniform

  const size_t Ks = (size_t)K;
  const int NT = K >> 7;      // K-tiles of 128
  const int NITER = K >> 8;   // 2 K-tiles per iteration

  v4i acc[8][4];
  v4i zero = {0, 0, 0, 0};
#pragma unroll
  for (int i = 0; i < 8; ++i)
#pragma unroll
    for (int j = 0; j < 4; ++j) acc[i][j] = zero;
  v4i af0, af1, af2, af3;
  v4i bf0, bf1, bf2, bf3, bf4, bf5, bf6, bf7;

  // ---- prologue: kt0 full (8 loads) + kt1 partial (7 loads) ----
  STAGE_AQ(0, 0, 0); STAGE_AQ(0, 0, 1); STAGE_AQ(0, 0, 2); STAGE_AQ(0, 0, 3);
  STAGE_BH(0, 0, 0, 0); STAGE_BH(0, 0, 0, 1);
  STAGE_BH(0, 0, 1, 0); STAGE_BH(0, 0, 1, 1);
  STAGE_AQ(1, 1, 0);
  STAGE_BH(1, 1, 0, 0); STAGE_BH(1, 1, 0, 1);
  STAGE_AQ(1, 1, 1);
  STAGE_BH(1, 1, 1, 0); STAGE_BH(1, 1, 1, 1);
  STAGE_AQ(1, 1, 2);
  WAITV7_();
  BAR_();

  for (int j = 0; j < NITER; ++j) {
    const int kt1 = 2 * j + 1;
    int ka = 2 * j + 2;
    if (ka >= NT) ka -= NT;  // last-iter wrap: wasted but valid loads
    int kb = 2 * j + 3;
    if (kb >= NT) kb -= NT;
    // p0: compute buf0 {B all + A q0}
    DS_B0(0) DS_A0(0, 0) DS_B1(0) DS_A1(0, 0)
    STAGE_AQ(1, kt1, 3);
    PH(0, 0);
    BAR_();
    // p1
    DS_A0(0, 1) DS_A1(0, 1)
    STAGE_BH(0, ka, 0, 0); STAGE_BH(0, ka, 0, 1); STAGE_AQ(0, ka, 0);
    PH(0, 1);
    BAR_();
    // p2
    DS_A0(0, 2) DS_A1(0, 2)
    STAGE_BH(0, ka, 1, 0); STAGE_BH(0, ka, 1, 1); STAGE_AQ(0, ka, 1);
    PH(0, 2);
    BAR_();
    // p3 (K-tile boundary)
    DS_A0(0, 3) DS_A1(0, 3)
    STAGE_AQ(0, ka, 2);
    PH(0, 3);
    WAITV7_();
    BAR_();
    // p4: compute buf1
    DS_B0(1) DS_A0(1, 0) DS_B1(1) DS_A1(1, 0)
    STAGE_AQ(0, ka, 3);
    PH(1, 0);
    BAR_();
    // p5
    DS_A0(1, 1) DS_A1(1, 1)
    STAGE_AQ(1, kb, 0);
    PH(1, 1);
    BAR_();
    // p6
    DS_A0(1, 2) DS_A1(1, 2)
    STAGE_BH(1, kb, 0, 0); STAGE_BH(1, kb, 0, 1); STAGE_AQ(1, kb, 1);
    PH(1, 2);
    BAR_();
    // p7 (K-tile boundary)
    DS_A0(1, 3) DS_A1(1, 3)
    STAGE_BH(1, kb, 1, 0); STAGE_BH(1, kb, 1, 1); STAGE_AQ(1, kb, 2);
    PH(1, 3);
    WAITV7_();
    BAR_();
  }

  // ---- epilogue: dequant (+GELU) and store ----
#pragma unroll
  for (int jj = 0; jj < 4; ++jj) {
    int col = tn0 + wn * 64 + jj * 16 + (lane & 15);
    float wsj = wsc[col];
    float zpj = wzp[col] - 128.0f;
    float bj = bias[col];
#pragma unroll
    for (int i = 0; i < 8; ++i) {
#pragma unroll
      for (int rg = 0; rg < 4; ++rg) {
        int row = tm0 + wm * 128 + i * 16 + (lane >> 4) * 4 + rg;
        float a = (float)acc[i][jj][rg];
        float o = sx[row] * wsj * (a - zpj * sumx[row]) + bj;
        if (GELU) o = 0.5f * o * (1.0f + erff(o * 0.70710678118654752f));
        OUT[(size_t)row * N + col] = o;
      }
    }
  }
}

extern "C" void kernel_launch(void* const* d_in, const int* in_sizes, int n_in,
                              void* d_out, int out_size, void* d_ws,
                              size_t ws_size, hipStream_t stream) {
  const float* x = (const float*)d_in[0];
  const int* w1q = (const int*)d_in[1];
  const float* w1s = (const float*)d_in[2];
  const float* w1zp = (const float*)d_in[3];
  const float* b1 = (const float*)d_in[4];
  const int* w2q = (const int*)d_in[5];
  const float* w2s = (const float*)d_in[6];
  const float* w2zp = (const float*)d_in[7];
  const float* b2 = (const float*)d_in[8];
  float* out = (float*)d_out;

  char* base = (char*)d_ws;
  size_t off = 0;
  auto take = [&](size_t b) {
    char* p = base + off;
    off += (b + 255) & ~(size_t)255;
    return p;
  };
  int8_t* q1 = (int8_t*)take((size_t)TT * DD);
  int8_t* q2 = (int8_t*)take((size_t)TT * HH);
  int8_t* w1b = (int8_t*)take((size_t)HH * DD);
  int8_t* w2b = (int8_t*)take((size_t)DD * HH);
  float* g = (float*)take((size_t)TT * HH * 4);
  float* s1 = (float*)take((size_t)TT * 4);
  float* sum1 = (float*)take((size_t)TT * 4);
  float* s2 = (float*)take((size_t)TT * 4);
  float* sum2 = (float*)take((size_t)TT * 4);

  hipLaunchKernelGGL(cvt_w, dim3(2048), dim3(256), 0, stream, w1q, w1b,
                     (int)((size_t)HH * DD / 16));
  hipLaunchKernelGGL(quant_x, dim3(TT), dim3(256), 0, stream, x, q1, s1, sum1);
  hipLaunchKernelGGL((gemm8p<true>), dim3(HH / 256, TT / 256), dim3(512),
                     131072, stream, q1, w1b, g, s1, sum1, w1s, w1zp, b1, TT,
                     HH, DD);
  hipLaunchKernelGGL(cvt_w, dim3(2048), dim3(256), 0, stream, w2q, w2b,
                     (int)((size_t)DD * HH / 16));
  hipLaunchKernelGGL(quant_g, dim3(TT), dim3(256), 0, stream, g, q2, s2, sum2);
  hipLaunchKernelGGL((gemm8p<false>), dim3(DD / 256, TT / 256), dim3(512),
                     131072, stream, q2, w2b, out, s2, sum2, w2s, w2zp, b2, TT,
                     DD, HH);
}